// Round 4
// baseline (86.739 us; speedup 1.0000x reference)
//
#include <hip/hip_runtime.h>

// GNNComm: out[i,:] = mean_{j!=i} relu(concat(m_i,m_j)@W1^T + b1) @ W2^T + b2
// N=2048, D=8, H=64.
//
// relu(z) = (z+|z|)/2 =>
//   S[i,h] = sum_j relu(a_ih + x_jh) = 0.5*(N*a_ih + SX_h + C_ih),
//   C_ih = sum_j |a_ih + x_jh|, a = X1[i]+b1, x = X2[j], SX = sum_j x_jh
// out[i,d] = 0.5*sum_h (C_ih + SX_h + N*a_ih - 2*relu(a_ih+x_ih)) W2[d,h]
//            / (N-1) + b2[d]
// abs trick matters: acc += |a+x| is 2 VALU/elem (abs is a free VOP3 input
// modifier); direct relu would be 3 (max-with-0 doesn't fold).
//
// R3 post-mortem: timed window = 40us harness ws-poison fill (untouchable)
// + our kernels + per-node gaps. This version: ONE worker kernel. Each
// (it,jc) block computes its own A-tile (registers) and X2-chunk (LDS)
// straight from msg/W1/b1 (~256 FMA/thread; msg+W1 are L2-resident), so
// the prep dispatch and the A/X2 global round-trip disappear. d_out is
// zeroed by a 64KB memset node; blocks atomicAdd their W2-projected
// contribution (512K fp32 atomics ~ 8MB write-through, cheap per R1's
// lesson that 2M was 32MB).

#define NN 2048
#define HH 64
#define DD 8

#define ITILES 32          // 32 i-tiles x 64 i
#define JCHUNKS 32         // 32 j-chunks x 64 j
#define JCHUNK (NN / JCHUNKS)
#define INV_SCALE (0.5f / (float)(NN - 1))

__device__ __forceinline__ float dot4(float4 a, float4 b) {
    return a.x * b.x + a.y * b.y + a.z * b.z + a.w * b.w;
}

// Block (it,jc): 64 i x 64 h x 64 j. Thread: hq=tid&15 (4 h's), il=tid>>4 (4 i's).
__global__ void __launch_bounds__(256, 4)
pair_fused(const float* __restrict__ msg,
           const float* __restrict__ W1,
           const float* __restrict__ b1,
           const float* __restrict__ W2,
           const float* __restrict__ b2,
           float* __restrict__ out) {
    __shared__ float4 sX2[JCHUNK * 16];   // [64 j][16 hq] = 16KB
    __shared__ float  T[64][68];          // per-block tile, padded
    __shared__ float4 sSXv[16];           // chunk column-sums of X2

    int it = blockIdx.x & (ITILES - 1);
    int jc = blockIdx.x >> 5;
    int hq = threadIdx.x & 15;
    int il = threadIdx.x >> 4;
    int h0 = hq * 4;
    int i0 = it * 64 + il * 4;
    bool des = (jc == it);                // diagonal block: owns per-i terms

    // ---- staging: compute A-frag (regs) and X2-chunk (LDS) from inputs ----
    const float4* m4 = (const float4*)msg;   // row i = 2 float4
    const float4* w4 = (const float4*)W1;    // row h = 4 float4
    float4 b1v = *(const float4*)&b1[h0];
    float bb[4] = {b1v.x, b1v.y, b1v.z, b1v.w};

    float4 wA[4][2], wB[4][2];               // W1 rows h0..h0+3, halves
#pragma unroll
    for (int hh = 0; hh < 4; ++hh) {
        wA[hh][0] = w4[(h0 + hh) * 4 + 0];
        wA[hh][1] = w4[(h0 + hh) * 4 + 1];
        wB[hh][0] = w4[(h0 + hh) * 4 + 2];
        wB[hh][1] = w4[(h0 + hh) * 4 + 3];
    }

    float a[4][4];
#pragma unroll
    for (int k = 0; k < 4; ++k) {
        float4 mi0 = m4[(i0 + k) * 2], mi1 = m4[(i0 + k) * 2 + 1];
#pragma unroll
        for (int hh = 0; hh < 4; ++hh)
            a[k][hh] = dot4(mi0, wA[hh][0]) + dot4(mi1, wA[hh][1]) + bb[hh];
    }
    {
        int jg = jc * JCHUNK + il * 4;       // this thread's 4 chunk rows
#pragma unroll
        for (int k = 0; k < 4; ++k) {
            float4 mj0 = m4[(jg + k) * 2], mj1 = m4[(jg + k) * 2 + 1];
            float4 xv;
            xv.x = dot4(mj0, wB[0][0]) + dot4(mj1, wB[0][1]);
            xv.y = dot4(mj0, wB[1][0]) + dot4(mj1, wB[1][1]);
            xv.z = dot4(mj0, wB[2][0]) + dot4(mj1, wB[2][1]);
            xv.w = dot4(mj0, wB[3][0]) + dot4(mj1, wB[3][1]);
            sX2[(il * 4 + k) * 16 + hq] = xv;
        }
    }

    float acc[4][4];
#pragma unroll
    for (int k = 0; k < 4; ++k)
#pragma unroll
        for (int hh = 0; hh < 4; ++hh)
            acc[k][hh] = 0.f;

    __syncthreads();

    // ---- hot loop: 2 VALU/elem ----
#pragma unroll 4
    for (int j = 0; j < JCHUNK; ++j) {
        float4 x = sX2[j * 16 + hq];
#pragma unroll
        for (int k = 0; k < 4; ++k) {
            acc[k][0] += __builtin_fabsf(a[k][0] + x.x);
            acc[k][1] += __builtin_fabsf(a[k][1] + x.y);
            acc[k][2] += __builtin_fabsf(a[k][2] + x.z);
            acc[k][3] += __builtin_fabsf(a[k][3] + x.w);
        }
    }

    const float* sX2f = (const float*)sX2;

    // chunk column-sums (wave-0 tail loop; stall hidden by 4 blocks/CU)
    if (threadIdx.x < 64) {
        float s0 = 0.f, s1 = 0.f, s2 = 0.f, s3 = 0.f;
#pragma unroll 8
        for (int j = 0; j < JCHUNK; j += 4) {
            s0 += sX2f[(j + 0) * 64 + threadIdx.x];
            s1 += sX2f[(j + 1) * 64 + threadIdx.x];
            s2 += sX2f[(j + 2) * 64 + threadIdx.x];
            s3 += sX2f[(j + 3) * 64 + threadIdx.x];
        }
        ((float*)sSXv)[threadIdx.x] = (s0 + s1) + (s2 + s3);
    }

    // write tile to LDS; diagonal block folds in N*a - 2*relu(a + x_i)
#pragma unroll
    for (int k = 0; k < 4; ++k) {
        float t0 = acc[k][0], t1 = acc[k][1], t2 = acc[k][2], t3 = acc[k][3];
        if (des) {
            int jl = il * 4 + k;  // local j index == local i index on diagonal
            float z0 = a[k][0] + sX2f[jl * 64 + h0 + 0];
            float z1 = a[k][1] + sX2f[jl * 64 + h0 + 1];
            float z2 = a[k][2] + sX2f[jl * 64 + h0 + 2];
            float z3 = a[k][3] + sX2f[jl * 64 + h0 + 3];
            t0 += (float)NN * a[k][0] - 2.f * (z0 > 0.f ? z0 : 0.f);
            t1 += (float)NN * a[k][1] - 2.f * (z1 > 0.f ? z1 : 0.f);
            t2 += (float)NN * a[k][2] - 2.f * (z2 > 0.f ? z2 : 0.f);
            t3 += (float)NN * a[k][3] - 2.f * (z3 > 0.f ? z3 : 0.f);
        }
        *(float4*)&T[il * 4 + k][h0] = make_float4(t0, t1, t2, t3);
    }
    __syncthreads();

    // project (T + sSX) onto W2 rows -> atomicAdd into out
    {
        int iL = threadIdx.x >> 3;        // 0..31
        int d  = threadIdx.x & 7;
        const float4* w2v = (const float4*)W2;  // [8][16]
        float s0 = 0.f, s1 = 0.f, c = 0.f;
#pragma unroll
        for (int hb = 0; hb < 16; ++hb) {
            float4 w  = w2v[d * 16 + hb];
            float4 t0 = *(const float4*)&T[iL][hb * 4];
            float4 t1 = *(const float4*)&T[iL + 32][hb * 4];
            float4 sx = sSXv[hb];
            s0 += t0.x * w.x + t0.y * w.y + t0.z * w.z + t0.w * w.w;
            s1 += t1.x * w.x + t1.y * w.y + t1.z * w.z + t1.w * w.w;
            c  += sx.x * w.x + sx.y * w.y + sx.z * w.z + sx.w * w.w;
        }
        float v0 = (s0 + c) * INV_SCALE;
        float v1 = (s1 + c) * INV_SCALE;
        if (des) {
            float bv = b2[d];
            v0 += bv;
            v1 += bv;
        }
        int ibase = it * 64;
        atomicAdd(&out[(ibase + iL) * DD + d], v0);
        atomicAdd(&out[(ibase + iL + 32) * DD + d], v1);
    }
}

extern "C" void kernel_launch(void* const* d_in, const int* in_sizes, int n_in,
                              void* d_out, int out_size, void* d_ws, size_t ws_size,
                              hipStream_t stream) {
    const float* msg = (const float*)d_in[0];  // [N, 8]
    const float* W1  = (const float*)d_in[1];  // [64, 16]
    const float* b1  = (const float*)d_in[2];  // [64]
    const float* W2  = (const float*)d_in[3];  // [8, 64]
    const float* b2  = (const float*)d_in[4];  // [8]
    float* out = (float*)d_out;                // [N, 8]

    hipMemsetAsync(out, 0, NN * DD * sizeof(float), stream);
    pair_fused<<<ITILES * JCHUNKS, 256, 0, stream>>>(msg, W1, b1, W2, b2, out);
}